// Round 7
// baseline (42963.968 us; speedup 1.0000x reference)
//
#include <hip/hip_runtime.h>

__device__ __forceinline__ float sigm(float x) { return 1.f / (1.f + expf(-x)); }

// H=256 E=512 B=32 Tt=512 Tm=1000 MEL=80 VOCAB=256; ws f32, out FLOAT32.
constexpr size_t O_ENC  = 0;                          // [32][512][512]
constexpr size_t O_DECH = O_ENC  + 32*512*512;        // [32][1000][256]
constexpr size_t O_EGT  = O_DECH + 32*1000*256;       // [2][256][1024] raw gate G
constexpr size_t O_SC   = O_EGT  + 2*256*1024;        // [32][4][512]
constexpr size_t O_EBAR = O_SC   + 32*4*512;          // [32][4][512]
constexpr size_t O_VO   = O_EBAR + 32*4*512;          // [32][512]
constexpr size_t O_AV   = O_VO   + 32*512;            // [32][512]
constexpr size_t O_XGD  = O_AV   + 32*512;            // [32][1024] raw gate G
constexpr size_t O_U    = O_XGD  + 32*1024;           // [4][512]
constexpr size_t O_SB   = O_U    + 4*512;             // [4] pad 16
constexpr size_t O_END  = O_SB   + 16;

// ---- eg[dir][v][G] = emb[v]·wih[G] + bih[G] + bhh[G] ----
__global__ void k_prepB(const float* __restrict__ emb,
                        const float* __restrict__ fw, const float* __restrict__ fb1, const float* __restrict__ fb2,
                        const float* __restrict__ bw, const float* __restrict__ bb1, const float* __restrict__ bb2,
                        float* __restrict__ egt) {
  int gid = blockIdx.x * 256 + threadIdx.x;    // < 524288
  int G = gid & 1023; int v = (gid >> 10) & 255; int dir = gid >> 18;
  const float* w = dir ? bw : fw;
  float acc = dir ? (bb1[G] + bb2[G]) : (fb1[G] + fb2[G]);
  const float4* a4 = (const float4*)(emb + (size_t)v * 256);
  const float4* w4 = (const float4*)(w + (size_t)G * 256);
  #pragma unroll 8
  for (int d = 0; d < 64; ++d) {
    float4 a = a4[d], b = w4[d];
    acc = fmaf(a.x, b.x, acc); acc = fmaf(a.y, b.y, acc);
    acc = fmaf(a.z, b.z, acc); acc = fmaf(a.w, b.w, acc);
  }
  egt[gid] = acc;
}

// ---- encoder scan, sync-free: 1 block per (dir,b) chain; thread = gate row G ----
__global__ __launch_bounds__(1024) void k_enc_simple(
    const float* __restrict__ whh_f, const float* __restrict__ whh_b,
    const float* __restrict__ egt, const int* __restrict__ text,
    float* __restrict__ enc) {
  const int chain = blockIdx.x;
  const int dir = chain >> 5, b = chain & 31;
  const int G = threadIdx.x;                    // gate row 0..1023
  __shared__ float sh_h[256];
  __shared__ float sh_g[1024];
  if (G < 256) sh_h[G] = 0.f;
  float cst = 0.f;
  const float* whh = dir ? whh_b : whh_f;
  const float* egd = egt + (size_t)dir * 262144;
  const float4* wrow = (const float4*)(whh + (size_t)G * 256);
  __syncthreads();
  for (int t = 0; t < 512; ++t) {
    const int tpos = dir ? (511 - t) : t;
    const int tok = text[b * 512 + tpos];
    float g = egd[(size_t)tok * 1024 + G];
    const float4* h4 = (const float4*)sh_h;
    #pragma unroll 8
    for (int d = 0; d < 64; ++d) {
      float4 h = h4[d], w = wrow[d];
      g = fmaf(w.x, h.x, g); g = fmaf(w.y, h.y, g);
      g = fmaf(w.z, h.z, g); g = fmaf(w.w, h.w, g);
    }
    sh_g[G] = g;
    __syncthreads();
    if (G < 256) {
      const int j = G;
      float ig = sigm(sh_g[j]), fg = sigm(sh_g[256 + j]);
      float gt = tanhf(sh_g[512 + j]), og = sigm(sh_g[768 + j]);
      cst = fg * cst + ig * gt;
      float hn = og * tanhf(cst);
      enc[((size_t)b * 512 + tpos) * 512 + dir * 256 + j] = hn;
      sh_h[j] = hn;
    }
    __syncthreads();
  }
}

// ---- u[h] = wk^T·bq per head; sbias[h] = bq_h·bk_h (query==bq collapse, exact) ----
__global__ void k_att1(const float* __restrict__ aiw, const float* __restrict__ aib,
                       float* __restrict__ u, float* __restrict__ sbias) {
  int h = blockIdx.x; int e = threadIdx.x;
  float acc = 0.f;
  for (int hd = 0; hd < 128; ++hd) {
    float qv = aib[h * 128 + hd];
    acc = fmaf(qv, aiw[((size_t)(512 + h * 128 + hd)) * 512 + e], acc);
  }
  u[h * 512 + e] = acc;
  if (e == 0) {
    float sb = 0.f;
    for (int hd = 0; hd < 128; ++hd)
      sb = fmaf(aib[h * 128 + hd], aib[512 + h * 128 + hd], sb);
    sbias[h] = sb;
  }
}

// ---- sc[b,h,t] = (enc[b,t]·u[h] + sbias[h]) / sqrt(128) ----
__global__ void k_att2(const float* __restrict__ enc, const float* __restrict__ u,
                       const float* __restrict__ sbias, float* __restrict__ sc) {
  const int b = blockIdx.x >> 7, tile = blockIdx.x & 127;
  const int wave = threadIdx.x >> 6, lane = threadIdx.x & 63;
  const int tk = tile * 4 + wave;
  const float4* erow = (const float4*)(enc + ((size_t)b * 512 + tk) * 512);
  float4 e0 = erow[lane * 2], e1 = erow[lane * 2 + 1];
  const float4* up = (const float4*)u;
  float acc[4];
  #pragma unroll
  for (int h = 0; h < 4; ++h) {
    float4 ua = up[h * 128 + lane * 2], ub = up[h * 128 + lane * 2 + 1];
    float a = 0.f;
    a = fmaf(e0.x, ua.x, a); a = fmaf(e0.y, ua.y, a); a = fmaf(e0.z, ua.z, a); a = fmaf(e0.w, ua.w, a);
    a = fmaf(e1.x, ub.x, a); a = fmaf(e1.y, ub.y, a); a = fmaf(e1.z, ub.z, a); a = fmaf(e1.w, ub.w, a);
    acc[h] = a;
  }
  #pragma unroll
  for (int h = 0; h < 4; ++h)
    for (int m = 32; m > 0; m >>= 1) acc[h] += __shfl_xor(acc[h], m);
  if (lane == 0) {
    #pragma unroll
    for (int h = 0; h < 4; ++h)
      sc[((size_t)(b * 4 + h)) * 512 + tk] = (acc[h] + sbias[h]) * 0.08838834764831845f;
  }
}

__global__ void k_smax(float* __restrict__ sc) {
  const int bh = blockIdx.x, tid = threadIdx.x;
  __shared__ float red[8];
  __shared__ float st0, st1;
  float v = sc[(size_t)bh * 512 + tid];
  float m = v;
  for (int k = 32; k > 0; k >>= 1) m = fmaxf(m, __shfl_xor(m, k));
  if ((tid & 63) == 0) red[tid >> 6] = m;
  __syncthreads();
  if (tid == 0) { float mm = red[0]; for (int i = 1; i < 8; ++i) mm = fmaxf(mm, red[i]); st0 = mm; }
  __syncthreads();
  float e = expf(v - st0);
  float s = e;
  for (int k = 32; k > 0; k >>= 1) s += __shfl_xor(s, k);
  if ((tid & 63) == 0) red[tid >> 6] = s;
  __syncthreads();
  if (tid == 0) { float ss = 0.f; for (int i = 0; i < 8; ++i) ss += red[i]; st1 = 1.f / ss; }
  __syncthreads();
  sc[(size_t)bh * 512 + tid] = e * st1;
}

__global__ void k_ebar(const float* __restrict__ sc, const float* __restrict__ enc,
                       float* __restrict__ ebar) {
  const int bh = blockIdx.x, tid = threadIdx.x;
  __shared__ float la[512];
  la[tid] = sc[(size_t)bh * 512 + tid];
  __syncthreads();
  const int b = bh >> 2;
  const float* eb = enc + (size_t)b * 512 * 512 + tid;
  float acc = 0.f;
  #pragma unroll 8
  for (int tk = 0; tk < 512; ++tk) acc = fmaf(la[tk], eb[(size_t)tk * 512], acc);
  ebar[(size_t)bh * 512 + tid] = acc;
}

__global__ void k_vout(const float* __restrict__ aiw, const float* __restrict__ aib,
                       const float* __restrict__ ebar, float* __restrict__ vo) {
  const int b = blockIdx.x, tid = threadIdx.x;
  __shared__ float leb[2048];
  for (int k = tid; k < 2048; k += 512) leb[k] = ebar[(size_t)b * 2048 + k];
  __syncthreads();
  const int h = tid >> 7;
  const float4* w4 = (const float4*)(aiw + (size_t)(1024 + tid) * 512);  // wv row
  const float4* eb4 = (const float4*)(leb + h * 512);
  float acc = aib[1024 + tid];                 // bv
  #pragma unroll 4
  for (int e = 0; e < 128; ++e) {
    float4 ww = w4[e], ee = eb4[e];
    acc = fmaf(ww.x, ee.x, acc); acc = fmaf(ww.y, ee.y, acc);
    acc = fmaf(ww.z, ee.z, acc); acc = fmaf(ww.w, ee.w, acc);
  }
  vo[(size_t)b * 512 + tid] = acc;
}

__global__ void k_oproj(const float* __restrict__ aow, const float* __restrict__ aob,
                        const float* __restrict__ vo, float* __restrict__ av) {
  const int b = blockIdx.x, tid = threadIdx.x;
  __shared__ float lvo[512];
  lvo[tid] = vo[(size_t)b * 512 + tid];
  __syncthreads();
  const float4* w4 = (const float4*)(aow + (size_t)tid * 512);
  const float4* v4 = (const float4*)lvo;
  float acc = aob[tid];
  #pragma unroll 4
  for (int e = 0; e < 128; ++e) {
    float4 ww = w4[e], ee = v4[e];
    acc = fmaf(ww.x, ee.x, acc); acc = fmaf(ww.y, ee.y, acc);
    acc = fmaf(ww.z, ee.z, acc); acc = fmaf(ww.w, ee.w, acc);
  }
  av[(size_t)b * 512 + tid] = acc;
}

__global__ void k_dgate(const float* __restrict__ dwih, const float* __restrict__ db1,
                        const float* __restrict__ db2, const float* __restrict__ av,
                        float* __restrict__ xgd) {
  const int b = blockIdx.x, G = threadIdx.x;   // 1024 threads
  __shared__ float lav[512];
  if (G < 512) lav[G] = av[(size_t)b * 512 + G];
  __syncthreads();
  const float4* w4 = (const float4*)(dwih + (size_t)G * 512);
  const float4* a4 = (const float4*)lav;
  float acc = db1[G] + db2[G];
  #pragma unroll 4
  for (int e = 0; e < 128; ++e) {
    float4 ww = w4[e], aa = a4[e];
    acc = fmaf(ww.x, aa.x, acc); acc = fmaf(ww.y, aa.y, acc);
    acc = fmaf(ww.z, aa.z, acc); acc = fmaf(ww.w, aa.w, acc);
  }
  xgd[(size_t)b * 1024 + G] = acc;
}

// ---- decoder scan, sync-free: 1 block per batch; thread = gate row G ----
__global__ __launch_bounds__(1024) void k_dec_simple(
    const float* __restrict__ dwhh, const float* __restrict__ xgd,
    float* __restrict__ dech) {
  const int b = blockIdx.x;
  const int G = threadIdx.x;
  __shared__ float sh_h[256];
  __shared__ float sh_g[1024];
  if (G < 256) sh_h[G] = 0.f;
  float cst = 0.f;
  const float xg = xgd[(size_t)b * 1024 + G];   // constant over t
  const float4* wrow = (const float4*)(dwhh + (size_t)G * 256);
  __syncthreads();
  for (int t = 0; t < 1000; ++t) {
    float g = xg;
    const float4* h4 = (const float4*)sh_h;
    #pragma unroll 8
    for (int d = 0; d < 64; ++d) {
      float4 h = h4[d], w = wrow[d];
      g = fmaf(w.x, h.x, g); g = fmaf(w.y, h.y, g);
      g = fmaf(w.z, h.z, g); g = fmaf(w.w, h.w, g);
    }
    sh_g[G] = g;
    __syncthreads();
    if (G < 256) {
      const int j = G;
      float ig = sigm(sh_g[j]), fg = sigm(sh_g[256 + j]);
      float gt = tanhf(sh_g[512 + j]), og = sigm(sh_g[768 + j]);
      cst = fg * cst + ig * gt;
      float hn = og * tanhf(cst);
      dech[((size_t)b * 1000 + t) * 256 + j] = hn;
      sh_h[j] = hn;
    }
    __syncthreads();
  }
}

// ---- projection: out = dech @ proj_w^T + proj_b, FLOAT32 out ----
__global__ __launch_bounds__(256) void k_proj(const float* __restrict__ dech,
                                              const float* __restrict__ pw,
                                              const float* __restrict__ pb,
                                              float* __restrict__ out) {
  __shared__ float lpw[80 * 260];
  __shared__ float lpb[80];
  const int tid = threadIdx.x;
  for (int i = tid; i < 20480; i += 256) lpw[(i >> 8) * 260 + (i & 255)] = pw[i];
  if (tid < 80) lpb[tid] = pb[tid];
  __syncthreads();
  const int row0 = blockIdx.x * 16;
  const int ri = tid >> 4, mi = tid & 15;
  const float4* dr = (const float4*)(dech + (size_t)(row0 + ri) * 256);
  #pragma unroll
  for (int mt = 0; mt < 5; ++mt) {
    const int m = mt * 16 + mi;
    float acc = lpb[m];
    const float4* pw4 = (const float4*)&lpw[m * 260];
    #pragma unroll 8
    for (int d4 = 0; d4 < 64; ++d4) {
      float4 w4 = pw4[d4]; float4 x4 = dr[d4];
      acc = fmaf(w4.x, x4.x, acc); acc = fmaf(w4.y, x4.y, acc);
      acc = fmaf(w4.z, x4.z, acc); acc = fmaf(w4.w, x4.w, acc);
    }
    out[(size_t)(row0 + ri) * 80 + m] = acc;    // f32 store — the fix
  }
}

extern "C" void kernel_launch(void* const* d_in, const int* in_sizes, int n_in,
                              void* d_out, int out_size, void* d_ws, size_t ws_size,
                              hipStream_t stream) {
  static const int SIG[21] = {16384, 2560000, 65536,
                              262144, 262144, 1024, 1024,      // enc_f
                              262144, 262144, 1024, 1024,      // enc_b
                              786432, 1536, 262144, 512,       // attn
                              524288, 262144, 1024, 1024,      // dec
                              20480, 80};                      // proj
  if (n_in != 21) return;
  for (int i = 0; i < 21; ++i) if (in_sizes[i] != SIG[i]) return;
  if (ws_size < O_END * sizeof(float)) return;
  if (out_size != 32 * 1000 * 80) return;

  const int* text = (const int*)d_in[0];
  const float* emb    = (const float*)d_in[2];
  const float* ef_wih = (const float*)d_in[3];
  const float* ef_whh = (const float*)d_in[4];
  const float* ef_bih = (const float*)d_in[5];
  const float* ef_bhh = (const float*)d_in[6];
  const float* eb_wih = (const float*)d_in[7];
  const float* eb_whh = (const float*)d_in[8];
  const float* eb_bih = (const float*)d_in[9];
  const float* eb_bhh = (const float*)d_in[10];
  const float* aiw    = (const float*)d_in[11];
  const float* aib    = (const float*)d_in[12];
  const float* aow    = (const float*)d_in[13];
  const float* aob    = (const float*)d_in[14];
  const float* dwih   = (const float*)d_in[15];
  const float* dwhh   = (const float*)d_in[16];
  const float* dbih   = (const float*)d_in[17];
  const float* dbhh   = (const float*)d_in[18];
  const float* pw     = (const float*)d_in[19];
  const float* pb     = (const float*)d_in[20];
  float* W = (float*)d_ws;
  float* out = (float*)d_out;

  k_prepB<<<2048, 256, 0, stream>>>(emb, ef_wih, ef_bih, ef_bhh,
                                    eb_wih, eb_bih, eb_bhh, W + O_EGT);
  k_enc_simple<<<64, 1024, 0, stream>>>(ef_whh, eb_whh, W + O_EGT, text, W + O_ENC);
  k_att1<<<4, 512, 0, stream>>>(aiw, aib, W + O_U, W + O_SB);
  k_att2<<<4096, 256, 0, stream>>>(W + O_ENC, W + O_U, W + O_SB, W + O_SC);
  k_smax<<<128, 512, 0, stream>>>(W + O_SC);
  k_ebar<<<128, 512, 0, stream>>>(W + O_SC, W + O_ENC, W + O_EBAR);
  k_vout<<<32, 512, 0, stream>>>(aiw, aib, W + O_EBAR, W + O_VO);
  k_oproj<<<32, 512, 0, stream>>>(aow, aob, W + O_VO, W + O_AV);
  k_dgate<<<32, 1024, 0, stream>>>(dwih, dbih, dbhh, W + O_AV, W + O_XGD);
  k_dec_simple<<<32, 1024, 0, stream>>>(dwhh, W + O_XGD, W + O_DECH);
  k_proj<<<2000, 256, 0, stream>>>(W + O_DECH, pw, pb, out);
}

// Round 8
// 7938.271 us; speedup vs baseline: 5.4123x; 5.4123x over previous
//
#include <hip/hip_runtime.h>

__device__ __forceinline__ float sigm(float x) { return 1.f / (1.f + expf(-x)); }

// H=256 E=512 B=32 Tt=512 Tm=1000 MEL=80 VOCAB=256; ws f32, out FLOAT32.
constexpr size_t O_ENC  = 0;                          // [32][512][512]
constexpr size_t O_DECH = O_ENC  + 8388608;           // [32][1000][256]
constexpr size_t O_EWPK = O_DECH + 8192000;           // [8][1024][64]  (dir*4+s, tid, i)
constexpr size_t O_DWPK = O_EWPK + 524288;            // [8][1024][32]  (s, tid, i)
constexpr size_t O_EGT  = O_DWPK + 262144;            // [2][256][1024] raw gate G
constexpr size_t O_SC   = O_EGT  + 524288;            // [32][4][512]
constexpr size_t O_EBAR = O_SC   + 65536;             // [32][4][512]
constexpr size_t O_VO   = O_EBAR + 65536;             // [32][512]
constexpr size_t O_AV   = O_VO   + 16384;             // [32][512]
constexpr size_t O_XGD  = O_AV   + 16384;             // [32][1024] raw gate G
constexpr size_t O_U    = O_XGD  + 32768;             // [4][512]
constexpr size_t O_SB   = O_U    + 2048;              // [4] pad 16
constexpr size_t O_HGE  = O_SB   + 16;                // [64][2][256]
constexpr size_t O_HGD  = O_HGE  + 32768;             // [32][2][256]
constexpr size_t O_CNT  = O_HGD  + 16384;             // 2048 u32
constexpr size_t O_END  = O_CNT  + 2048;

// ---- prep A: recurrent weight packs (per-thread contiguous), zero hg + counters ----
__global__ void k_prepA(const float* __restrict__ ef_whh, const float* __restrict__ eb_whh,
                        const float* __restrict__ d_whh,
                        float* __restrict__ ewpk, float* __restrict__ dwpk,
                        float* __restrict__ hgz, unsigned int* __restrict__ cnts) {
  int gid = blockIdx.x * 256 + threadIdx.x;
  if (gid < 524288) {              // ewpk[((dir*4+s)*1024 + tid)*64 + i] = whh[G][c]
    int i = gid & 63; int u = gid >> 6; int tid = u & 1023; int du = u >> 10;
    int dir = du >> 2, s = du & 3;
    int q = tid >> 8, r = tid & 255, tg = r >> 6, j = r & 63;
    int G = tg * 256 + s * 64 + j, c = q * 64 + i;
    ewpk[gid] = (dir ? eb_whh : ef_whh)[(size_t)G * 256 + c];
  } else if (gid < 786432) {       // dwpk[(s*1024 + tid)*32 + i] = dwhh[G][c]
    int e = gid - 524288;
    int i = e & 31; int u = e >> 5; int tid = u & 1023; int s = u >> 10;
    int q = tid >> 7, r = tid & 127, tg = r >> 5, j = r & 31;
    int G = tg * 256 + s * 32 + j, c = q * 32 + i;
    dwpk[e] = d_whh[(size_t)G * 256 + c];
  } else if (gid < 835584) {       // zero hg broadcast buffers (HGE+HGD = 49152)
    hgz[gid - 786432] = 0.f;
  } else if (gid < 837632) {
    cnts[gid - 835584] = 0u;
  }
}

// ---- prep B: eg[dir][v][G] = emb[v]·wih[G] + bih[G] + bhh[G] ----
__global__ void k_prepB(const float* __restrict__ emb,
                        const float* __restrict__ fw, const float* __restrict__ fb1, const float* __restrict__ fb2,
                        const float* __restrict__ bw, const float* __restrict__ bb1, const float* __restrict__ bb2,
                        float* __restrict__ egt) {
  int gid = blockIdx.x * 256 + threadIdx.x;    // < 524288
  int G = gid & 1023; int v = (gid >> 10) & 255; int dir = gid >> 18;
  const float* w = dir ? bw : fw;
  float acc = dir ? (bb1[G] + bb2[G]) : (fb1[G] + fb2[G]);
  const float4* a4 = (const float4*)(emb + (size_t)v * 256);
  const float4* w4 = (const float4*)(w + (size_t)G * 256);
  #pragma unroll 8
  for (int d = 0; d < 64; ++d) {
    float4 a = a4[d], b = w4[d];
    acc = fmaf(a.x, b.x, acc); acc = fmaf(a.y, b.y, acc);
    acc = fmaf(a.z, b.z, acc); acc = fmaf(a.w, b.w, acc);
  }
  egt[gid] = acc;
}

// ---- encoder scan: 64 chains x 4 slices = 256 WGs, weights in VGPRs, L2-atomic sync ----
// (function-equivalence of this multi-WG scan to the sync-free scan was established
//  in rounds 3-5: bit-identical outputs across both structures)
__global__ __launch_bounds__(1024, 4) void k_enc(
    const float* __restrict__ ewpk, const float* __restrict__ egt,
    const int* __restrict__ text, float* __restrict__ enc,
    float* __restrict__ hg, unsigned int* __restrict__ cnt) {
  const int wg = blockIdx.x;
  const int chain = wg & 63, s = wg >> 6;      // slice-major: chain's 4 WGs share wg%8 XCD
  const int dir = chain >> 5, b = chain & 31;
  const int tid = threadIdx.x;
  const int q = tid >> 8;
  __shared__ float sh_h[256];
  __shared__ float sh_p[1024];
  __shared__ float sh_a[256];
  float w[64];
  {
    const float* wp = ewpk + ((size_t)((dir * 4 + s) * 1024 + tid)) * 64;
    #pragma unroll
    for (int i = 0; i < 64; ++i) w[i] = wp[i];
  }
  if (tid < 256) sh_h[tid] = 0.f;
  float cst = 0.f;
  const float* egd = egt + (size_t)dir * 262144;
  unsigned int* mycnt = cnt + chain * 16;
  float* hgc = hg + (size_t)chain * 512;
  int budget = 8000000;
  __syncthreads();
  for (int t = 0; t < 512; ++t) {
    const int tpos = dir ? (511 - t) : t;
    const int tok = text[b * 512 + tpos];
    float egv = 0.f;
    if (tid < 256)
      egv = egd[(size_t)tok * 1024 + ((tid >> 6) * 256 + s * 64 + (tid & 63))];
    float a0 = 0.f, a1 = 0.f, a2 = 0.f, a3 = 0.f;
    const float* hc = sh_h + q * 64;
    #pragma unroll
    for (int i0 = 0; i0 < 64; i0 += 16) {
      float4 h0 = *(const float4*)(hc + i0);
      float4 h1 = *(const float4*)(hc + i0 + 4);
      float4 h2 = *(const float4*)(hc + i0 + 8);
      float4 h3 = *(const float4*)(hc + i0 + 12);
      a0 = fmaf(w[i0+0], h0.x, a0); a0 = fmaf(w[i0+1], h0.y, a0); a0 = fmaf(w[i0+2], h0.z, a0); a0 = fmaf(w[i0+3], h0.w, a0);
      a1 = fmaf(w[i0+4], h1.x, a1); a1 = fmaf(w[i0+5], h1.y, a1); a1 = fmaf(w[i0+6], h1.z, a1); a1 = fmaf(w[i0+7], h1.w, a1);
      a2 = fmaf(w[i0+8], h2.x, a2); a2 = fmaf(w[i0+9], h2.y, a2); a2 = fmaf(w[i0+10], h2.z, a2); a2 = fmaf(w[i0+11], h2.w, a2);
      a3 = fmaf(w[i0+12], h3.x, a3); a3 = fmaf(w[i0+13], h3.y, a3); a3 = fmaf(w[i0+14], h3.z, a3); a3 = fmaf(w[i0+15], h3.w, a3);
    }
    sh_p[tid] = (a0 + a1) + (a2 + a3);
    __syncthreads();
    if (tid < 256) {
      float g = ((sh_p[tid] + sh_p[256 + tid]) + (sh_p[512 + tid] + sh_p[768 + tid])) + egv;
      sh_a[tid] = ((tid >> 6) == 2) ? tanhf(g) : sigm(g);
    }
    __syncthreads();
    if (tid < 64) {   // wave 0: state update, publish slice (agent scope = coherence point)
      float ig = sh_a[tid], fg = sh_a[64 + tid], gg = sh_a[128 + tid], og = sh_a[192 + tid];
      cst = fg * cst + ig * gg;
      float hn = og * tanhf(cst);
      enc[((size_t)b * 512 + tpos) * 512 + dir * 256 + s * 64 + tid] = hn;
      if (t < 511)
        __hip_atomic_store(&hgc[(t & 1) * 256 + s * 64 + tid], hn,
                           __ATOMIC_RELAXED, __HIP_MEMORY_SCOPE_AGENT);
    }
    if (t < 511) {
      // release-inc by tid0 (same wave as publishes -> vmcnt drain orders them)
      if (tid == 0) {
        __hip_atomic_fetch_add(mycnt, 1u, __ATOMIC_RELEASE, __HIP_MEMORY_SCOPE_AGENT);
        const unsigned int tgt = 4u * (unsigned)(t + 1);
        while (budget > 0 &&
               __hip_atomic_load(mycnt, __ATOMIC_ACQUIRE, __HIP_MEMORY_SCOPE_AGENT) < tgt) {
          --budget; __builtin_amdgcn_s_sleep(2);
        }
      }
      __syncthreads();
      if (tid < 256)
        sh_h[tid] = __hip_atomic_load(&hgc[(t & 1) * 256 + tid],
                                      __ATOMIC_RELAXED, __HIP_MEMORY_SCOPE_AGENT);
      __syncthreads();
    }
  }
}

// ---- u[h] = wk^T·bq per head; sbias[h] = bq_h·bk_h (query==bq collapse, exact) ----
__global__ void k_att1(const float* __restrict__ aiw, const float* __restrict__ aib,
                       float* __restrict__ u, float* __restrict__ sbias) {
  int h = blockIdx.x; int e = threadIdx.x;
  float acc = 0.f;
  for (int hd = 0; hd < 128; ++hd) {
    float qv = aib[h * 128 + hd];
    acc = fmaf(qv, aiw[((size_t)(512 + h * 128 + hd)) * 512 + e], acc);
  }
  u[h * 512 + e] = acc;
  if (e == 0) {
    float sb = 0.f;
    for (int hd = 0; hd < 128; ++hd)
      sb = fmaf(aib[h * 128 + hd], aib[512 + h * 128 + hd], sb);
    sbias[h] = sb;
  }
}

__global__ void k_att2(const float* __restrict__ enc, const float* __restrict__ u,
                       const float* __restrict__ sbias, float* __restrict__ sc) {
  const int b = blockIdx.x >> 7, tile = blockIdx.x & 127;
  const int wave = threadIdx.x >> 6, lane = threadIdx.x & 63;
  const int tk = tile * 4 + wave;
  const float4* erow = (const float4*)(enc + ((size_t)b * 512 + tk) * 512);
  float4 e0 = erow[lane * 2], e1 = erow[lane * 2 + 1];
  const float4* up = (const float4*)u;
  float acc[4];
  #pragma unroll
  for (int h = 0; h < 4; ++h) {
    float4 ua = up[h * 128 + lane * 2], ub = up[h * 128 + lane * 2 + 1];
    float a = 0.f;
    a = fmaf(e0.x, ua.x, a); a = fmaf(e0.y, ua.y, a); a = fmaf(e0.z, ua.z, a); a = fmaf(e0.w, ua.w, a);
    a = fmaf(e1.x, ub.x, a); a = fmaf(e1.y, ub.y, a); a = fmaf(e1.z, ub.z, a); a = fmaf(e1.w, ub.w, a);
    acc[h] = a;
  }
  #pragma unroll
  for (int h = 0; h < 4; ++h)
    for (int m = 32; m > 0; m >>= 1) acc[h] += __shfl_xor(acc[h], m);
  if (lane == 0) {
    #pragma unroll
    for (int h = 0; h < 4; ++h)
      sc[((size_t)(b * 4 + h)) * 512 + tk] = (acc[h] + sbias[h]) * 0.08838834764831845f;
  }
}

__global__ void k_smax(float* __restrict__ sc) {
  const int bh = blockIdx.x, tid = threadIdx.x;
  __shared__ float red[8];
  __shared__ float st0, st1;
  float v = sc[(size_t)bh * 512 + tid];
  float m = v;
  for (int k = 32; k > 0; k >>= 1) m = fmaxf(m, __shfl_xor(m, k));
  if ((tid & 63) == 0) red[tid >> 6] = m;
  __syncthreads();
  if (tid == 0) { float mm = red[0]; for (int i = 1; i < 8; ++i) mm = fmaxf(mm, red[i]); st0 = mm; }
  __syncthreads();
  float e = expf(v - st0);
  float s = e;
  for (int k = 32; k > 0; k >>= 1) s += __shfl_xor(s, k);
  if ((tid & 63) == 0) red[tid >> 6] = s;
  __syncthreads();
  if (tid == 0) { float ss = 0.f; for (int i = 0; i < 8; ++i) ss += red[i]; st1 = 1.f / ss; }
  __syncthreads();
  sc[(size_t)bh * 512 + tid] = e * st1;
}

__global__ void k_ebar(const float* __restrict__ sc, const float* __restrict__ enc,
                       float* __restrict__ ebar) {
  const int bh = blockIdx.x, tid = threadIdx.x;
  __shared__ float la[512];
  la[tid] = sc[(size_t)bh * 512 + tid];
  __syncthreads();
  const int b = bh >> 2;
  const float* eb = enc + (size_t)b * 512 * 512 + tid;
  float acc = 0.f;
  #pragma unroll 8
  for (int tk = 0; tk < 512; ++tk) acc = fmaf(la[tk], eb[(size_t)tk * 512], acc);
  ebar[(size_t)bh * 512 + tid] = acc;
}

__global__ void k_vout(const float* __restrict__ aiw, const float* __restrict__ aib,
                       const float* __restrict__ ebar, float* __restrict__ vo) {
  const int b = blockIdx.x, tid = threadIdx.x;
  __shared__ float leb[2048];
  for (int k = tid; k < 2048; k += 512) leb[k] = ebar[(size_t)b * 2048 + k];
  __syncthreads();
  const int h = tid >> 7;
  const float4* w4 = (const float4*)(aiw + (size_t)(1024 + tid) * 512);  // wv row
  const float4* eb4 = (const float4*)(leb + h * 512);
  float acc = aib[1024 + tid];                 // bv
  #pragma unroll 4
  for (int e = 0; e < 128; ++e) {
    float4 ww = w4[e], ee = eb4[e];
    acc = fmaf(ww.x, ee.x, acc); acc = fmaf(ww.y, ee.y, acc);
    acc = fmaf(ww.z, ee.z, acc); acc = fmaf(ww.w, ee.w, acc);
  }
  vo[(size_t)b * 512 + tid] = acc;
}

__global__ void k_oproj(const float* __restrict__ aow, const float* __restrict__ aob,
                        const float* __restrict__ vo, float* __restrict__ av) {
  const int b = blockIdx.x, tid = threadIdx.x;
  __shared__ float lvo[512];
  lvo[tid] = vo[(size_t)b * 512 + tid];
  __syncthreads();
  const float4* w4 = (const float4*)(aow + (size_t)tid * 512);
  const float4* v4 = (const float4*)lvo;
  float acc = aob[tid];
  #pragma unroll 4
  for (int e = 0; e < 128; ++e) {
    float4 ww = w4[e], ee = v4[e];
    acc = fmaf(ww.x, ee.x, acc); acc = fmaf(ww.y, ee.y, acc);
    acc = fmaf(ww.z, ee.z, acc); acc = fmaf(ww.w, ee.w, acc);
  }
  av[(size_t)b * 512 + tid] = acc;
}

__global__ void k_dgate(const float* __restrict__ dwih, const float* __restrict__ db1,
                        const float* __restrict__ db2, const float* __restrict__ av,
                        float* __restrict__ xgd) {
  const int b = blockIdx.x, G = threadIdx.x;   // 1024 threads
  __shared__ float lav[512];
  if (G < 512) lav[G] = av[(size_t)b * 512 + G];
  __syncthreads();
  const float4* w4 = (const float4*)(dwih + (size_t)G * 512);
  const float4* a4 = (const float4*)lav;
  float acc = db1[G] + db2[G];
  #pragma unroll 4
  for (int e = 0; e < 128; ++e) {
    float4 ww = w4[e], aa = a4[e];
    acc = fmaf(ww.x, aa.x, acc); acc = fmaf(ww.y, aa.y, acc);
    acc = fmaf(ww.z, aa.z, acc); acc = fmaf(ww.w, aa.w, acc);
  }
  xgd[(size_t)b * 1024 + G] = acc;
}

// ---- decoder scan: 32 chains x 8 slices = 256 WGs, weights in VGPRs, L2-atomic sync ----
__global__ __launch_bounds__(1024, 4) void k_dec(
    const float* __restrict__ dwpk, const float* __restrict__ xgd,
    float* __restrict__ dech, float* __restrict__ hg, unsigned int* __restrict__ cnt) {
  const int wg = blockIdx.x;
  const int b = wg & 31, s = wg >> 5;          // slice-major: chain's 8 WGs share wg%8 XCD
  const int tid = threadIdx.x;
  const int q = tid >> 7;
  __shared__ float sh_h[256];
  __shared__ float sh_p[1024];
  __shared__ float sh_a[128];
  __shared__ float sh_eg[128];
  float w[32];
  {
    const float* wp = dwpk + ((size_t)(s * 1024 + tid)) * 32;
    #pragma unroll
    for (int i = 0; i < 32; ++i) w[i] = wp[i];
  }
  if (tid < 128)
    sh_eg[tid] = xgd[(size_t)b * 1024 + ((tid >> 5) * 256 + s * 32 + (tid & 31))];
  if (tid < 256) sh_h[tid] = 0.f;
  float cst = 0.f;
  unsigned int* mycnt = cnt + 1024 + b * 16;
  float* hgc = hg + (size_t)b * 512;
  int budget = 8000000;
  __syncthreads();
  for (int t = 0; t < 1000; ++t) {
    float a0 = 0.f, a1 = 0.f;
    const float* hc = sh_h + q * 32;
    #pragma unroll
    for (int i0 = 0; i0 < 32; i0 += 8) {
      float4 h0 = *(const float4*)(hc + i0);
      float4 h1 = *(const float4*)(hc + i0 + 4);
      a0 = fmaf(w[i0+0], h0.x, a0); a0 = fmaf(w[i0+1], h0.y, a0); a0 = fmaf(w[i0+2], h0.z, a0); a0 = fmaf(w[i0+3], h0.w, a0);
      a1 = fmaf(w[i0+4], h1.x, a1); a1 = fmaf(w[i0+5], h1.y, a1); a1 = fmaf(w[i0+6], h1.z, a1); a1 = fmaf(w[i0+7], h1.w, a1);
    }
    sh_p[tid] = a0 + a1;
    __syncthreads();
    if (tid < 128) {
      float g = sh_eg[tid];
      #pragma unroll
      for (int k = 0; k < 8; ++k) g += sh_p[k * 128 + tid];
      sh_a[tid] = ((tid >> 5) == 2) ? tanhf(g) : sigm(g);
    }
    __syncthreads();
    if (tid < 32) {   // wave 0: state update + publish slice
      float ig = sh_a[tid], fg = sh_a[32 + tid], gg = sh_a[64 + tid], og = sh_a[96 + tid];
      cst = fg * cst + ig * gg;
      float hn = og * tanhf(cst);
      dech[((size_t)b * 1000 + t) * 256 + s * 32 + tid] = hn;
      if (t < 999)
        __hip_atomic_store(&hgc[(t & 1) * 256 + s * 32 + tid], hn,
                           __ATOMIC_RELAXED, __HIP_MEMORY_SCOPE_AGENT);
    }
    if (t < 999) {
      if (tid == 0) {
        __hip_atomic_fetch_add(mycnt, 1u, __ATOMIC_RELEASE, __HIP_MEMORY_SCOPE_AGENT);
        const unsigned int tgt = 8u * (unsigned)(t + 1);
        while (budget > 0 &&
               __hip_atomic_load(mycnt, __ATOMIC_ACQUIRE, __HIP_MEMORY_SCOPE_AGENT) < tgt) {
          --budget; __builtin_amdgcn_s_sleep(2);
        }
      }
      __syncthreads();
      if (tid < 256)
        sh_h[tid] = __hip_atomic_load(&hgc[(t & 1) * 256 + tid],
                                      __ATOMIC_RELAXED, __HIP_MEMORY_SCOPE_AGENT);
      __syncthreads();
    }
  }
}

// ---- projection: out = dech @ proj_w^T + proj_b, FLOAT32 out ----
__global__ __launch_bounds__(256) void k_proj(const float* __restrict__ dech,
                                              const float* __restrict__ pw,
                                              const float* __restrict__ pb,
                                              float* __restrict__ out) {
  __shared__ float lpw[80 * 260];
  __shared__ float lpb[80];
  const int tid = threadIdx.x;
  for (int i = tid; i < 20480; i += 256) lpw[(i >> 8) * 260 + (i & 255)] = pw[i];
  if (tid < 80) lpb[tid] = pb[tid];
  __syncthreads();
  const int row0 = blockIdx.x * 16;
  const int ri = tid >> 4, mi = tid & 15;
  const float4* dr = (const float4*)(dech + (size_t)(row0 + ri) * 256);
  #pragma unroll
  for (int mt = 0; mt < 5; ++mt) {
    const int m = mt * 16 + mi;
    float acc = lpb[m];
    const float4* pw4 = (const float4*)&lpw[m * 260];
    #pragma unroll 8
    for (int d4 = 0; d4 < 64; ++d4) {
      float4 w4 = pw4[d4]; float4 x4 = dr[d4];
      acc = fmaf(w4.x, x4.x, acc); acc = fmaf(w4.y, x4.y, acc);
      acc = fmaf(w4.z, x4.z, acc); acc = fmaf(w4.w, x4.w, acc);
    }
    out[(size_t)(row0 + ri) * 80 + m] = acc;
  }
}

extern "C" void kernel_launch(void* const* d_in, const int* in_sizes, int n_in,
                              void* d_out, int out_size, void* d_ws, size_t ws_size,
                              hipStream_t stream) {
  static const int SIG[21] = {16384, 2560000, 65536,
                              262144, 262144, 1024, 1024,      // enc_f
                              262144, 262144, 1024, 1024,      // enc_b
                              786432, 1536, 262144, 512,       // attn
                              524288, 262144, 1024, 1024,      // dec
                              20480, 80};                      // proj
  if (n_in != 21) return;
  for (int i = 0; i < 21; ++i) if (in_sizes[i] != SIG[i]) return;
  if (ws_size < O_END * sizeof(float)) return;
  if (out_size != 32 * 1000 * 80) return;

  const int* text = (const int*)d_in[0];
  const float* emb    = (const float*)d_in[2];
  const float* ef_wih = (const float*)d_in[3];
  const float* ef_whh = (const float*)d_in[4];
  const float* ef_bih = (const float*)d_in[5];
  const float* ef_bhh = (const float*)d_in[6];
  const float* eb_wih = (const float*)d_in[7];
  const float* eb_whh = (const float*)d_in[8];
  const float* eb_bih = (const float*)d_in[9];
  const float* eb_bhh = (const float*)d_in[10];
  const float* aiw    = (const float*)d_in[11];
  const float* aib    = (const float*)d_in[12];
  const float* aow    = (const float*)d_in[13];
  const float* aob    = (const float*)d_in[14];
  const float* dwih   = (const float*)d_in[15];
  const float* dwhh   = (const float*)d_in[16];
  const float* dbih   = (const float*)d_in[17];
  const float* dbhh   = (const float*)d_in[18];
  const float* pw     = (const float*)d_in[19];
  const float* pb     = (const float*)d_in[20];
  float* W = (float*)d_ws;
  unsigned int* cnts = (unsigned int*)(W + O_CNT);
  float* out = (float*)d_out;

  k_prepA<<<3272, 256, 0, stream>>>(ef_whh, eb_whh, dwhh,
                                    W + O_EWPK, W + O_DWPK, W + O_HGE, cnts);
  k_prepB<<<2048, 256, 0, stream>>>(emb, ef_wih, ef_bih, ef_bhh,
                                    eb_wih, eb_bih, eb_bhh, W + O_EGT);
  k_enc<<<256, 1024, 0, stream>>>(W + O_EWPK, W + O_EGT, text, W + O_ENC,
                                  W + O_HGE, cnts);
  k_att1<<<4, 512, 0, stream>>>(aiw, aib, W + O_U, W + O_SB);
  k_att2<<<4096, 256, 0, stream>>>(W + O_ENC, W + O_U, W + O_SB, W + O_SC);
  k_smax<<<128, 512, 0, stream>>>(W + O_SC);
  k_ebar<<<128, 512, 0, stream>>>(W + O_SC, W + O_ENC, W + O_EBAR);
  k_vout<<<32, 512, 0, stream>>>(aiw, aib, W + O_EBAR, W + O_VO);
  k_oproj<<<32, 512, 0, stream>>>(aow, aob, W + O_VO, W + O_AV);
  k_dgate<<<32, 1024, 0, stream>>>(dwih, dbih, dbhh, W + O_AV, W + O_XGD);
  k_dec<<<256, 1024, 0, stream>>>(W + O_DWPK, W + O_XGD, W + O_DECH,
                                  W + O_HGD, cnts);
  k_proj<<<2000, 256, 0, stream>>>(W + O_DECH, pw, pb, out);
}

// Round 9
// 6002.931 us; speedup vs baseline: 7.1572x; 1.3224x over previous
//
#include <hip/hip_runtime.h>

__device__ __forceinline__ float sigm(float x) { return 1.f / (1.f + expf(-x)); }

// H=256 E=512 B=32 Tt=512 Tm=1000 MEL=80 VOCAB=256; ws f32, out FLOAT32.
constexpr size_t O_ENC  = 0;                          // [32][512][512]
constexpr size_t O_DECH = O_ENC  + 8388608;           // [32][1000][256]
constexpr size_t O_EWPK = O_DECH + 8192000;           // [8][1024][64]  (dir*4+s, tid, i)
constexpr size_t O_DWPK = O_EWPK + 524288;            // [4][1024][64]  (s, tid, i)
constexpr size_t O_EGT  = O_DWPK + 262144;            // [2][256][1024] raw gate G
constexpr size_t O_SC   = O_EGT  + 524288;            // [32][4][512]
constexpr size_t O_EBAR = O_SC   + 65536;             // [32][4][512]
constexpr size_t O_XGD  = O_EBAR + 65536;             // [32][1024] raw gate G
constexpr size_t O_U    = O_XGD  + 32768;             // [4][512]
constexpr size_t O_SB   = O_U    + 2048;              // [4] pad 16
constexpr size_t O_HGE  = O_SB   + 16;                // [64][2][256]
constexpr size_t O_HGD  = O_HGE  + 32768;             // [32][2][256]
constexpr size_t O_FLG  = O_HGD  + 16384;             // enc: 64x16 u32, dec: 32x16 u32
constexpr size_t O_END  = O_FLG  + 2048;

// ---- prep A: weight packs (per-thread contiguous, 64/thread both scans), zero hg+flags ----
__global__ void k_prepA(const float* __restrict__ ef_whh, const float* __restrict__ eb_whh,
                        const float* __restrict__ d_whh,
                        float* __restrict__ ewpk, float* __restrict__ dwpk,
                        float* __restrict__ hgz, unsigned int* __restrict__ flg) {
  int gid = blockIdx.x * 256 + threadIdx.x;
  if (gid < 524288) {              // ewpk[((dir*4+s)*1024 + tid)*64 + i] = whh[G][c]
    int i = gid & 63; int u = gid >> 6; int tid = u & 1023; int du = u >> 10;
    int dir = du >> 2, s = du & 3;
    int q = tid >> 8, r = tid & 255, tg = r >> 6, j = r & 63;
    int G = tg * 256 + s * 64 + j, c = q * 64 + i;
    ewpk[gid] = (dir ? eb_whh : ef_whh)[(size_t)G * 256 + c];
  } else if (gid < 786432) {       // dwpk[(s*1024 + tid)*64 + i] = dwhh[G][c]
    int e = gid - 524288;
    int i = e & 63; int u = e >> 6; int tid = u & 1023; int s = u >> 10;  // s<4
    int q = tid >> 8, r = tid & 255, tg = r >> 6, j = r & 63;
    int G = tg * 256 + s * 64 + j, c = q * 64 + i;
    dwpk[e] = d_whh[(size_t)G * 256 + c];
  } else if (gid < 835584) {       // zero hg broadcast buffers (HGE+HGD = 49152)
    hgz[gid - 786432] = 0.f;
  } else if (gid < 837632) {       // zero flags
    flg[gid - 835584] = 0u;
  }
}

// ---- prep B: eg[dir][v][G] = emb[v]·wih[G] + bih[G] + bhh[G] ----
__global__ void k_prepB(const float* __restrict__ emb,
                        const float* __restrict__ fw, const float* __restrict__ fb1, const float* __restrict__ fb2,
                        const float* __restrict__ bw, const float* __restrict__ bb1, const float* __restrict__ bb2,
                        float* __restrict__ egt) {
  int gid = blockIdx.x * 256 + threadIdx.x;    // < 524288
  int G = gid & 1023; int v = (gid >> 10) & 255; int dir = gid >> 18;
  const float* w = dir ? bw : fw;
  float acc = dir ? (bb1[G] + bb2[G]) : (fb1[G] + fb2[G]);
  const float4* a4 = (const float4*)(emb + (size_t)v * 256);
  const float4* w4 = (const float4*)(w + (size_t)G * 256);
  #pragma unroll 8
  for (int d = 0; d < 64; ++d) {
    float4 a = a4[d], b = w4[d];
    acc = fmaf(a.x, b.x, acc); acc = fmaf(a.y, b.y, acc);
    acc = fmaf(a.z, b.z, acc); acc = fmaf(a.w, b.w, acc);
  }
  egt[gid] = acc;
}

// ---- encoder scan: 64 chains x 4 slices = 256 WGs; flag sync (no RMW) ----
__global__ __launch_bounds__(1024, 4) void k_enc(
    const float* __restrict__ ewpk, const float* __restrict__ egt,
    const int* __restrict__ text, float* __restrict__ enc,
    float* __restrict__ hg, unsigned int* __restrict__ flg) {
  const int wg = blockIdx.x;
  const int chain = wg & 63, s = wg >> 6;      // slice-major: chain's WGs share wg%8 XCD
  const int dir = chain >> 5, b = chain & 31;
  const int tid = threadIdx.x;
  const int q = tid >> 8;
  __shared__ float sh_h[256];
  __shared__ float sh_p[1024];
  __shared__ float sh_a[256];
  float w[64];
  {
    const float* wp = ewpk + ((size_t)((dir * 4 + s) * 1024 + tid)) * 64;
    #pragma unroll
    for (int i = 0; i < 64; ++i) w[i] = wp[i];
  }
  if (tid < 256) sh_h[tid] = 0.f;
  float cst = 0.f;
  const float* egd = egt + (size_t)dir * 262144;
  unsigned int* myflg = flg + chain * 16;
  float* hgc = hg + (size_t)chain * 512;
  int budget = 8000000;
  __syncthreads();
  for (int t = 0; t < 512; ++t) {
    const int tpos = dir ? (511 - t) : t;
    const int tok = text[b * 512 + tpos];
    float egv = 0.f;
    if (tid < 256)
      egv = egd[(size_t)tok * 1024 + ((tid >> 6) * 256 + s * 64 + (tid & 63))];
    float a0 = 0.f, a1 = 0.f, a2 = 0.f, a3 = 0.f;
    const float* hc = sh_h + q * 64;
    #pragma unroll
    for (int i0 = 0; i0 < 64; i0 += 16) {
      float4 h0 = *(const float4*)(hc + i0);
      float4 h1 = *(const float4*)(hc + i0 + 4);
      float4 h2 = *(const float4*)(hc + i0 + 8);
      float4 h3 = *(const float4*)(hc + i0 + 12);
      a0 = fmaf(w[i0+0], h0.x, a0); a0 = fmaf(w[i0+1], h0.y, a0); a0 = fmaf(w[i0+2], h0.z, a0); a0 = fmaf(w[i0+3], h0.w, a0);
      a1 = fmaf(w[i0+4], h1.x, a1); a1 = fmaf(w[i0+5], h1.y, a1); a1 = fmaf(w[i0+6], h1.z, a1); a1 = fmaf(w[i0+7], h1.w, a1);
      a2 = fmaf(w[i0+8], h2.x, a2); a2 = fmaf(w[i0+9], h2.y, a2); a2 = fmaf(w[i0+10], h2.z, a2); a2 = fmaf(w[i0+11], h2.w, a2);
      a3 = fmaf(w[i0+12], h3.x, a3); a3 = fmaf(w[i0+13], h3.y, a3); a3 = fmaf(w[i0+14], h3.z, a3); a3 = fmaf(w[i0+15], h3.w, a3);
    }
    sh_p[tid] = (a0 + a1) + (a2 + a3);
    __syncthreads();
    if (tid < 256) {
      float g = ((sh_p[tid] + sh_p[256 + tid]) + (sh_p[512 + tid] + sh_p[768 + tid])) + egv;
      sh_a[tid] = ((tid >> 6) == 2) ? tanhf(g) : sigm(g);
    }
    __syncthreads();
    if (tid < 64) {   // wave 0: state update, publish slice, release flag, THEN output store
      float ig = sh_a[tid], fg = sh_a[64 + tid], gg = sh_a[128 + tid], og = sh_a[192 + tid];
      cst = fg * cst + ig * gg;
      float hn = og * tanhf(cst);
      if (t < 511) {
        __hip_atomic_store(&hgc[(t & 1) * 256 + s * 64 + tid], hn,
                           __ATOMIC_RELAXED, __HIP_MEMORY_SCOPE_AGENT);
        if (tid == 0)   // same wave as publishes -> vmcnt drain covers them
          __hip_atomic_store(&myflg[s], (unsigned)(t + 1),
                             __ATOMIC_RELEASE, __HIP_MEMORY_SCOPE_AGENT);
      }
      enc[((size_t)b * 512 + tpos) * 512 + dir * 256 + s * 64 + tid] = hn;  // overlaps poll
    }
    if (t < 511) {
      if (tid < 64) {   // wave 0 polls all 4 flags in parallel (lanes mod 4)
        const unsigned tgt = (unsigned)(t + 1);
        while (budget > 0) {
          unsigned v = __hip_atomic_load(&myflg[tid & 3], __ATOMIC_ACQUIRE,
                                         __HIP_MEMORY_SCOPE_AGENT);
          if (__all((int)(v >= tgt))) break;
          --budget;
          __builtin_amdgcn_s_sleep(1);
        }
      }
      __syncthreads();
      if (tid < 256)
        sh_h[tid] = __hip_atomic_load(&hgc[(t & 1) * 256 + tid],
                                      __ATOMIC_RELAXED, __HIP_MEMORY_SCOPE_AGENT);
      __syncthreads();
    }
  }
}

// ---- u[h] = wk^T·bq per head; sbias[h] = bq_h·bk_h (query==bq collapse, exact) ----
__global__ void k_att1(const float* __restrict__ aiw, const float* __restrict__ aib,
                       float* __restrict__ u, float* __restrict__ sbias) {
  int h = blockIdx.x; int e = threadIdx.x;
  float acc = 0.f;
  for (int hd = 0; hd < 128; ++hd) {
    float qv = aib[h * 128 + hd];
    acc = fmaf(qv, aiw[((size_t)(512 + h * 128 + hd)) * 512 + e], acc);
  }
  u[h * 512 + e] = acc;
  if (e == 0) {
    float sb = 0.f;
    for (int hd = 0; hd < 128; ++hd)
      sb = fmaf(aib[h * 128 + hd], aib[512 + h * 128 + hd], sb);
    sbias[h] = sb;
  }
}

__global__ void k_att2(const float* __restrict__ enc, const float* __restrict__ u,
                       const float* __restrict__ sbias, float* __restrict__ sc) {
  const int b = blockIdx.x >> 7, tile = blockIdx.x & 127;
  const int wave = threadIdx.x >> 6, lane = threadIdx.x & 63;
  const int tk = tile * 4 + wave;
  const float4* erow = (const float4*)(enc + ((size_t)b * 512 + tk) * 512);
  float4 e0 = erow[lane * 2], e1 = erow[lane * 2 + 1];
  const float4* up = (const float4*)u;
  float acc[4];
  #pragma unroll
  for (int h = 0; h < 4; ++h) {
    float4 ua = up[h * 128 + lane * 2], ub = up[h * 128 + lane * 2 + 1];
    float a = 0.f;
    a = fmaf(e0.x, ua.x, a); a = fmaf(e0.y, ua.y, a); a = fmaf(e0.z, ua.z, a); a = fmaf(e0.w, ua.w, a);
    a = fmaf(e1.x, ub.x, a); a = fmaf(e1.y, ub.y, a); a = fmaf(e1.z, ub.z, a); a = fmaf(e1.w, ub.w, a);
    acc[h] = a;
  }
  #pragma unroll
  for (int h = 0; h < 4; ++h)
    for (int m = 32; m > 0; m >>= 1) acc[h] += __shfl_xor(acc[h], m);
  if (lane == 0) {
    #pragma unroll
    for (int h = 0; h < 4; ++h)
      sc[((size_t)(b * 4 + h)) * 512 + tk] = (acc[h] + sbias[h]) * 0.08838834764831845f;
  }
}

__global__ void k_smax(float* __restrict__ sc) {
  const int bh = blockIdx.x, tid = threadIdx.x;
  __shared__ float red[8];
  __shared__ float st0, st1;
  float v = sc[(size_t)bh * 512 + tid];
  float m = v;
  for (int k = 32; k > 0; k >>= 1) m = fmaxf(m, __shfl_xor(m, k));
  if ((tid & 63) == 0) red[tid >> 6] = m;
  __syncthreads();
  if (tid == 0) { float mm = red[0]; for (int i = 1; i < 8; ++i) mm = fmaxf(mm, red[i]); st0 = mm; }
  __syncthreads();
  float e = expf(v - st0);
  float s = e;
  for (int k = 32; k > 0; k >>= 1) s += __shfl_xor(s, k);
  if ((tid & 63) == 0) red[tid >> 6] = s;
  __syncthreads();
  if (tid == 0) { float ss = 0.f; for (int i = 0; i < 8; ++i) ss += red[i]; st1 = 1.f / ss; }
  __syncthreads();
  sc[(size_t)bh * 512 + tid] = e * st1;
}

__global__ void k_ebar(const float* __restrict__ sc, const float* __restrict__ enc,
                       float* __restrict__ ebar) {
  const int bh = blockIdx.x, tid = threadIdx.x;
  __shared__ float la[512];
  la[tid] = sc[(size_t)bh * 512 + tid];
  __syncthreads();
  const int b = bh >> 2;
  const float* eb = enc + (size_t)b * 512 * 512 + tid;
  float acc = 0.f;
  #pragma unroll 8
  for (int tk = 0; tk < 512; ++tk) acc = fmaf(la[tk], eb[(size_t)tk * 512], acc);
  ebar[(size_t)bh * 512 + tid] = acc;
}

// ---- fused vout+oproj+dgate: per-batch, LDS hand-off (3 GEMVs, 1 launch) ----
__global__ __launch_bounds__(1024) void k_avx(
    const float* __restrict__ aiw, const float* __restrict__ aib,
    const float* __restrict__ aow, const float* __restrict__ aob,
    const float* __restrict__ dwih, const float* __restrict__ db1,
    const float* __restrict__ db2, const float* __restrict__ ebar,
    float* __restrict__ xgd) {
  const int b = blockIdx.x, tid = threadIdx.x;
  __shared__ float leb[2048];
  __shared__ float lvo[512];
  __shared__ float lav[512];
  leb[tid] = ebar[(size_t)b * 2048 + tid];
  leb[1024 + tid] = ebar[(size_t)b * 2048 + 1024 + tid];
  __syncthreads();
  if (tid < 512) {                 // stage 1: vo[c] = wv[c]·ebar[b,c>>7] + bv[c]
    const int h = tid >> 7;
    const float4* w4 = (const float4*)(aiw + (size_t)(1024 + tid) * 512);
    const float4* e4 = (const float4*)(leb + h * 512);
    float acc = aib[1024 + tid];
    #pragma unroll 4
    for (int e = 0; e < 128; ++e) {
      float4 ww = w4[e], ee = e4[e];
      acc = fmaf(ww.x, ee.x, acc); acc = fmaf(ww.y, ee.y, acc);
      acc = fmaf(ww.z, ee.z, acc); acc = fmaf(ww.w, ee.w, acc);
    }
    lvo[tid] = acc;
  }
  __syncthreads();
  if (tid < 512) {                 // stage 2: av[e] = out_w[e]·vo + out_b[e]
    const float4* w4 = (const float4*)(aow + (size_t)tid * 512);
    const float4* v4 = (const float4*)lvo;
    float acc = aob[tid];
    #pragma unroll 4
    for (int e = 0; e < 128; ++e) {
      float4 ww = w4[e], ee = v4[e];
      acc = fmaf(ww.x, ee.x, acc); acc = fmaf(ww.y, ee.y, acc);
      acc = fmaf(ww.z, ee.z, acc); acc = fmaf(ww.w, ee.w, acc);
    }
    lav[tid] = acc;
  }
  __syncthreads();
  {                                 // stage 3: xgd[G] = dwih[G]·av + dbih[G]+dbhh[G]
    const int G = tid;
    const float4* w4 = (const float4*)(dwih + (size_t)G * 512);
    const float4* a4 = (const float4*)lav;
    float acc = db1[G] + db2[G];
    #pragma unroll 4
    for (int e = 0; e < 128; ++e) {
      float4 ww = w4[e], aa = a4[e];
      acc = fmaf(ww.x, aa.x, acc); acc = fmaf(ww.y, aa.y, acc);
      acc = fmaf(ww.z, aa.z, acc); acc = fmaf(ww.w, aa.w, acc);
    }
    xgd[(size_t)b * 1024 + G] = acc;
  }
}

// ---- decoder scan: 32 chains x 4 slices = 128 WGs; flag sync; xg constant over t ----
__global__ __launch_bounds__(1024, 4) void k_dec(
    const float* __restrict__ dwpk, const float* __restrict__ xgd,
    float* __restrict__ dech, float* __restrict__ hg, unsigned int* __restrict__ flg) {
  const int wg = blockIdx.x;
  const int b = wg & 31, s = wg >> 5;          // slice-major: chain's WGs share wg%8 XCD
  const int tid = threadIdx.x;
  const int q = tid >> 8;
  __shared__ float sh_h[256];
  __shared__ float sh_p[1024];
  __shared__ float sh_a[256];
  float w[64];
  {
    const float* wp = dwpk + ((size_t)(s * 1024 + tid)) * 64;
    #pragma unroll
    for (int i = 0; i < 64; ++i) w[i] = wp[i];
  }
  float xg = 0.f;
  if (tid < 256)
    xg = xgd[(size_t)b * 1024 + ((tid >> 6) * 256 + s * 64 + (tid & 63))];
  if (tid < 256) sh_h[tid] = 0.f;
  float cst = 0.f;
  unsigned int* myflg = flg + 1024 + b * 16;
  float* hgc = hg + (size_t)b * 512;
  int budget = 8000000;
  __syncthreads();
  for (int t = 0; t < 1000; ++t) {
    float a0 = 0.f, a1 = 0.f, a2 = 0.f, a3 = 0.f;
    const float* hc = sh_h + q * 64;
    #pragma unroll
    for (int i0 = 0; i0 < 64; i0 += 16) {
      float4 h0 = *(const float4*)(hc + i0);
      float4 h1 = *(const float4*)(hc + i0 + 4);
      float4 h2 = *(const float4*)(hc + i0 + 8);
      float4 h3 = *(const float4*)(hc + i0 + 12);
      a0 = fmaf(w[i0+0], h0.x, a0); a0 = fmaf(w[i0+1], h0.y, a0); a0 = fmaf(w[i0+2], h0.z, a0); a0 = fmaf(w[i0+3], h0.w, a0);
      a1 = fmaf(w[i0+4], h1.x, a1); a1 = fmaf(w[i0+5], h1.y, a1); a1 = fmaf(w[i0+6], h1.z, a1); a1 = fmaf(w[i0+7], h1.w, a1);
      a2 = fmaf(w[i0+8], h2.x, a2); a2 = fmaf(w[i0+9], h2.y, a2); a2 = fmaf(w[i0+10], h2.z, a2); a2 = fmaf(w[i0+11], h2.w, a2);
      a3 = fmaf(w[i0+12], h3.x, a3); a3 = fmaf(w[i0+13], h3.y, a3); a3 = fmaf(w[i0+14], h3.z, a3); a3 = fmaf(w[i0+15], h3.w, a3);
    }
    sh_p[tid] = (a0 + a1) + (a2 + a3);
    __syncthreads();
    if (tid < 256) {
      float g = ((sh_p[tid] + sh_p[256 + tid]) + (sh_p[512 + tid] + sh_p[768 + tid])) + xg;
      sh_a[tid] = ((tid >> 6) == 2) ? tanhf(g) : sigm(g);
    }
    __syncthreads();
    if (tid < 64) {
      float ig = sh_a[tid], fg = sh_a[64 + tid], gg = sh_a[128 + tid], og = sh_a[192 + tid];
      cst = fg * cst + ig * gg;
      float hn = og * tanhf(cst);
      if (t < 999) {
        __hip_atomic_store(&hgc[(t & 1) * 256 + s * 64 + tid], hn,
                           __ATOMIC_RELAXED, __HIP_MEMORY_SCOPE_AGENT);
        if (tid == 0)
          __hip_atomic_store(&myflg[s], (unsigned)(t + 1),
                             __ATOMIC_RELEASE, __HIP_MEMORY_SCOPE_AGENT);
      }
      dech[((size_t)b * 1000 + t) * 256 + s * 64 + tid] = hn;   // overlaps poll
    }
    if (t < 999) {
      if (tid < 64) {
        const unsigned tgt = (unsigned)(t + 1);
        while (budget > 0) {
          unsigned v = __hip_atomic_load(&myflg[tid & 3], __ATOMIC_ACQUIRE,
                                         __HIP_MEMORY_SCOPE_AGENT);
          if (__all((int)(v >= tgt))) break;
          --budget;
          __builtin_amdgcn_s_sleep(1);
        }
      }
      __syncthreads();
      if (tid < 256)
        sh_h[tid] = __hip_atomic_load(&hgc[(t & 1) * 256 + tid],
                                      __ATOMIC_RELAXED, __HIP_MEMORY_SCOPE_AGENT);
      __syncthreads();
    }
  }
}

// ---- projection: out = dech @ proj_w^T + proj_b, FLOAT32 out ----
__global__ __launch_bounds__(256) void k_proj(const float* __restrict__ dech,
                                              const float* __restrict__ pw,
                                              const float* __restrict__ pb,
                                              float* __restrict__ out) {
  __shared__ float lpw[80 * 260];
  __shared__ float lpb[80];
  const int tid = threadIdx.x;
  for (int i = tid; i < 20480; i += 256) lpw[(i >> 8) * 260 + (i & 255)] = pw[i];
  if (tid < 80) lpb[tid] = pb[tid];
  __syncthreads();
  const int row0 = blockIdx.x * 16;
  const int ri = tid >> 4, mi = tid & 15;
  const float4* dr = (const float4*)(dech + (size_t)(row0 + ri) * 256);
  #pragma unroll
  for (int mt = 0; mt < 5; ++mt) {
    const int m = mt * 16 + mi;
    float acc = lpb[m];
    const float4* pw4 = (const float4*)&lpw[m * 260];
    #pragma unroll 8
    for (int d4 = 0; d4 < 64; ++d4) {
      float4 w4 = pw4[d4]; float4 x4 = dr[d4];
      acc = fmaf(w4.x, x4.x, acc); acc = fmaf(w4.y, x4.y, acc);
      acc = fmaf(w4.z, x4.z, acc); acc = fmaf(w4.w, x4.w, acc);
    }
    out[(size_t)(row0 + ri) * 80 + m] = acc;
  }
}

extern "C" void kernel_launch(void* const* d_in, const int* in_sizes, int n_in,
                              void* d_out, int out_size, void* d_ws, size_t ws_size,
                              hipStream_t stream) {
  static const int SIG[21] = {16384, 2560000, 65536,
                              262144, 262144, 1024, 1024,      // enc_f
                              262144, 262144, 1024, 1024,      // enc_b
                              786432, 1536, 262144, 512,       // attn
                              524288, 262144, 1024, 1024,      // dec
                              20480, 80};                      // proj
  if (n_in != 21) return;
  for (int i = 0; i < 21; ++i) if (in_sizes[i] != SIG[i]) return;
  if (ws_size < O_END * sizeof(float)) return;
  if (out_size != 32 * 1000 * 80) return;

  const int* text = (const int*)d_in[0];
  const float* emb    = (const float*)d_in[2];
  const float* ef_wih = (const float*)d_in[3];
  const float* ef_whh = (const float*)d_in[4];
  const float* ef_bih = (const float*)d_in[5];
  const float* ef_bhh = (const float*)d_in[6];
  const float* eb_wih = (const float*)d_in[7];
  const float* eb_whh = (const float*)d_in[8];
  const float* eb_bih = (const float*)d_in[9];
  const float* eb_bhh = (const float*)d_in[10];
  const float* aiw    = (const float*)d_in[11];
  const float* aib    = (const float*)d_in[12];
  const float* aow    = (const float*)d_in[13];
  const float* aob    = (const float*)d_in[14];
  const float* dwih   = (const float*)d_in[15];
  const float* dwhh   = (const float*)d_in[16];
  const float* dbih   = (const float*)d_in[17];
  const float* dbhh   = (const float*)d_in[18];
  const float* pw     = (const float*)d_in[19];
  const float* pb     = (const float*)d_in[20];
  float* W = (float*)d_ws;
  unsigned int* flg = (unsigned int*)(W + O_FLG);
  float* out = (float*)d_out;

  k_prepA<<<3272, 256, 0, stream>>>(ef_whh, eb_whh, dwhh,
                                    W + O_EWPK, W + O_DWPK, W + O_HGE, flg);
  k_prepB<<<2048, 256, 0, stream>>>(emb, ef_wih, ef_bih, ef_bhh,
                                    eb_wih, eb_bih, eb_bhh, W + O_EGT);
  k_enc<<<256, 1024, 0, stream>>>(W + O_EWPK, W + O_EGT, text, W + O_ENC,
                                  W + O_HGE, flg);
  k_att1<<<4, 512, 0, stream>>>(aiw, aib, W + O_U, W + O_SB);
  k_att2<<<4096, 256, 0, stream>>>(W + O_ENC, W + O_U, W + O_SB, W + O_SC);
  k_smax<<<128, 512, 0, stream>>>(W + O_SC);
  k_ebar<<<128, 512, 0, stream>>>(W + O_SC, W + O_ENC, W + O_EBAR);
  k_avx<<<32, 1024, 0, stream>>>(aiw, aib, aow, aob, dwih, dbih, dbhh,
                                 W + O_EBAR, W + O_XGD);
  k_dec<<<128, 1024, 0, stream>>>(W + O_DWPK, W + O_XGD, W + O_DECH,
                                  W + O_HGD, flg);
  k_proj<<<2000, 256, 0, stream>>>(W + O_DECH, pw, pb, out);
}

// Round 10
// 3514.898 us; speedup vs baseline: 12.2234x; 1.7079x over previous
//
#include <hip/hip_runtime.h>

__device__ __forceinline__ float sigm(float x) { return 1.f / (1.f + expf(-x)); }

union fu32 { float f; unsigned u; };
__device__ __forceinline__ unsigned long long packh(float h, unsigned tag) {
  fu32 c; c.f = h; return ((unsigned long long)tag << 32) | (unsigned long long)c.u;
}

// H=256 E=512 B=32 Tt=512 Tm=1000 MEL=80 VOCAB=256; ws f32, out FLOAT32.
constexpr size_t O_ENC  = 0;                          // [32][512][512]
constexpr size_t O_DECH = O_ENC  + 8388608;           // [32][1000][256]
constexpr size_t O_EWPK = O_DECH + 8192000;           // [8][1024][64]  (dir*4+s, tid, i)
constexpr size_t O_DWPK = O_EWPK + 524288;            // [4][1024][64]  (s, tid, i)
constexpr size_t O_EGT  = O_DWPK + 262144;            // [2][256][1024] raw gate G
constexpr size_t O_SC   = O_EGT  + 524288;            // [32][4][512]
constexpr size_t O_EBAR = O_SC   + 65536;             // [32][4][512]
constexpr size_t O_XGD  = O_EBAR + 65536;             // [32][1024] raw gate G
constexpr size_t O_U    = O_XGD  + 32768;             // [4][512]
constexpr size_t O_SB   = O_U    + 2048;              // [4] pad 16
constexpr size_t O_HGE  = O_SB   + 16;                // ull [64][2][256] = 65536 f
constexpr size_t O_HGD  = O_HGE  + 65536;             // ull [32][2][256] = 32768 f
constexpr size_t O_END  = O_HGD  + 32768;

// ---- prep A: weight packs (per-thread contiguous, 64/thread both scans) ----
// (hg buffers need no init: readers poll for exact tag == t+1, poison can't match)
__global__ void k_prepA(const float* __restrict__ ef_whh, const float* __restrict__ eb_whh,
                        const float* __restrict__ d_whh,
                        float* __restrict__ ewpk, float* __restrict__ dwpk) {
  int gid = blockIdx.x * 256 + threadIdx.x;
  if (gid < 524288) {              // ewpk[((dir*4+s)*1024 + tid)*64 + i] = whh[G][c]
    int i = gid & 63; int u = gid >> 6; int tid = u & 1023; int du = u >> 10;
    int dir = du >> 2, s = du & 3;
    int q = tid >> 8, r = tid & 255, tg = r >> 6, j = r & 63;
    int G = tg * 256 + s * 64 + j, c = q * 64 + i;
    ewpk[gid] = (dir ? eb_whh : ef_whh)[(size_t)G * 256 + c];
  } else if (gid < 786432) {       // dwpk[(s*1024 + tid)*64 + i] = dwhh[G][c]
    int e = gid - 524288;
    int i = e & 63; int u = e >> 6; int tid = u & 1023; int s = u >> 10;  // s<4
    int q = tid >> 8, r = tid & 255, tg = r >> 6, j = r & 63;
    int G = tg * 256 + s * 64 + j, c = q * 64 + i;
    dwpk[e] = d_whh[(size_t)G * 256 + c];
  }
}

// ---- prep B: eg[dir][v][G] = emb[v]·wih[G] + bih[G] + bhh[G] ----
__global__ void k_prepB(const float* __restrict__ emb,
                        const float* __restrict__ fw, const float* __restrict__ fb1, const float* __restrict__ fb2,
                        const float* __restrict__ bw, const float* __restrict__ bb1, const float* __restrict__ bb2,
                        float* __restrict__ egt) {
  int gid = blockIdx.x * 256 + threadIdx.x;    // < 524288
  int G = gid & 1023; int v = (gid >> 10) & 255; int dir = gid >> 18;
  const float* w = dir ? bw : fw;
  float acc = dir ? (bb1[G] + bb2[G]) : (fb1[G] + fb2[G]);
  const float4* a4 = (const float4*)(emb + (size_t)v * 256);
  const float4* w4 = (const float4*)(w + (size_t)G * 256);
  #pragma unroll 8
  for (int d = 0; d < 64; ++d) {
    float4 a = a4[d], b = w4[d];
    acc = fmaf(a.x, b.x, acc); acc = fmaf(a.y, b.y, acc);
    acc = fmaf(a.z, b.z, acc); acc = fmaf(a.w, b.w, acc);
  }
  egt[gid] = acc;
}

// ---- encoder scan: 64 chains x 4 slices = 256 WGs; packed (tag|h) sync ----
__global__ __launch_bounds__(1024, 4) void k_enc(
    const float* __restrict__ ewpk, const float* __restrict__ egt,
    const int* __restrict__ text, float* __restrict__ enc,
    unsigned long long* __restrict__ hg) {
  const int wg = blockIdx.x;
  const int chain = wg & 63, s = wg >> 6;      // slice-major: chain's WGs share wg%8 XCD
  const int dir = chain >> 5, b = chain & 31;
  const int tid = threadIdx.x;
  const int q = tid >> 8;
  __shared__ float sh_h[256];
  __shared__ float sh_p[1024];
  __shared__ float sh_a[256];
  float w[64];
  {
    const float* wp = ewpk + ((size_t)((dir * 4 + s) * 1024 + tid)) * 64;
    #pragma unroll
    for (int i = 0; i < 64; ++i) w[i] = wp[i];
  }
  if (tid < 256) sh_h[tid] = 0.f;
  float cst = 0.f;
  const float* egd = egt + (size_t)dir * 262144;
  unsigned long long* hgc = hg + (size_t)chain * 512;
  int budget = 20000000;
  __syncthreads();
  for (int t = 0; t < 512; ++t) {
    const int tpos = dir ? (511 - t) : t;
    const int tok = text[b * 512 + tpos];
    float egv = 0.f;
    if (tid < 256)
      egv = egd[(size_t)tok * 1024 + ((tid >> 6) * 256 + s * 64 + (tid & 63))];
    float a0 = 0.f, a1 = 0.f, a2 = 0.f, a3 = 0.f;
    const float* hc = sh_h + q * 64;
    #pragma unroll
    for (int i0 = 0; i0 < 64; i0 += 16) {
      float4 h0 = *(const float4*)(hc + i0);
      float4 h1 = *(const float4*)(hc + i0 + 4);
      float4 h2 = *(const float4*)(hc + i0 + 8);
      float4 h3 = *(const float4*)(hc + i0 + 12);
      a0 = fmaf(w[i0+0], h0.x, a0); a0 = fmaf(w[i0+1], h0.y, a0); a0 = fmaf(w[i0+2], h0.z, a0); a0 = fmaf(w[i0+3], h0.w, a0);
      a1 = fmaf(w[i0+4], h1.x, a1); a1 = fmaf(w[i0+5], h1.y, a1); a1 = fmaf(w[i0+6], h1.z, a1); a1 = fmaf(w[i0+7], h1.w, a1);
      a2 = fmaf(w[i0+8], h2.x, a2); a2 = fmaf(w[i0+9], h2.y, a2); a2 = fmaf(w[i0+10], h2.z, a2); a2 = fmaf(w[i0+11], h2.w, a2);
      a3 = fmaf(w[i0+12], h3.x, a3); a3 = fmaf(w[i0+13], h3.y, a3); a3 = fmaf(w[i0+14], h3.z, a3); a3 = fmaf(w[i0+15], h3.w, a3);
    }
    sh_p[tid] = (a0 + a1) + (a2 + a3);
    __syncthreads();
    if (tid < 256) {
      float g = ((sh_p[tid] + sh_p[256 + tid]) + (sh_p[512 + tid] + sh_p[768 + tid])) + egv;
      sh_a[tid] = ((tid >> 6) == 2) ? tanhf(g) : sigm(g);
    }
    __syncthreads();
    if (tid < 64) {   // wave 0: state update; publish (tag|h) — data IS the flag
      float ig = sh_a[tid], fg = sh_a[64 + tid], gg = sh_a[128 + tid], og = sh_a[192 + tid];
      cst = fg * cst + ig * gg;
      float hn = og * tanhf(cst);
      if (t < 511)
        __hip_atomic_store(&hgc[(t & 1) * 256 + s * 64 + tid], packh(hn, (unsigned)(t + 1)),
                           __ATOMIC_RELAXED, __HIP_MEMORY_SCOPE_AGENT);
      enc[((size_t)b * 512 + tpos) * 512 + dir * 256 + s * 64 + tid] = hn;  // off crit. path
    }
    if (t < 511) {
      if (tid < 256) {   // poll own element: tag match delivers h in the same word
        const unsigned tgt = (unsigned)(t + 1);
        unsigned long long v;
        for (;;) {
          v = __hip_atomic_load(&hgc[(t & 1) * 256 + tid],
                                __ATOMIC_RELAXED, __HIP_MEMORY_SCOPE_AGENT);
          if ((unsigned)(v >> 32) == tgt || --budget <= 0) break;
          __builtin_amdgcn_s_sleep(1);
        }
        fu32 c; c.u = (unsigned)v;
        sh_h[tid] = c.f;
      }
      __syncthreads();
    }
  }
}

// ---- u[h] = wk^T·bq per head; sbias[h] = bq_h·bk_h (query==bq collapse, exact) ----
__global__ void k_att1(const float* __restrict__ aiw, const float* __restrict__ aib,
                       float* __restrict__ u, float* __restrict__ sbias) {
  int h = blockIdx.x; int e = threadIdx.x;
  float acc = 0.f;
  for (int hd = 0; hd < 128; ++hd) {
    float qv = aib[h * 128 + hd];
    acc = fmaf(qv, aiw[((size_t)(512 + h * 128 + hd)) * 512 + e], acc);
  }
  u[h * 512 + e] = acc;
  if (e == 0) {
    float sb = 0.f;
    for (int hd = 0; hd < 128; ++hd)
      sb = fmaf(aib[h * 128 + hd], aib[512 + h * 128 + hd], sb);
    sbias[h] = sb;
  }
}

__global__ void k_att2(const float* __restrict__ enc, const float* __restrict__ u,
                       const float* __restrict__ sbias, float* __restrict__ sc) {
  const int b = blockIdx.x >> 7, tile = blockIdx.x & 127;
  const int wave = threadIdx.x >> 6, lane = threadIdx.x & 63;
  const int tk = tile * 4 + wave;
  const float4* erow = (const float4*)(enc + ((size_t)b * 512 + tk) * 512);
  float4 e0 = erow[lane * 2], e1 = erow[lane * 2 + 1];
  const float4* up = (const float4*)u;
  float acc[4];
  #pragma unroll
  for (int h = 0; h < 4; ++h) {
    float4 ua = up[h * 128 + lane * 2], ub = up[h * 128 + lane * 2 + 1];
    float a = 0.f;
    a = fmaf(e0.x, ua.x, a); a = fmaf(e0.y, ua.y, a); a = fmaf(e0.z, ua.z, a); a = fmaf(e0.w, ua.w, a);
    a = fmaf(e1.x, ub.x, a); a = fmaf(e1.y, ub.y, a); a = fmaf(e1.z, ub.z, a); a = fmaf(e1.w, ub.w, a);
    acc[h] = a;
  }
  #pragma unroll
  for (int h = 0; h < 4; ++h)
    for (int m = 32; m > 0; m >>= 1) acc[h] += __shfl_xor(acc[h], m);
  if (lane == 0) {
    #pragma unroll
    for (int h = 0; h < 4; ++h)
      sc[((size_t)(b * 4 + h)) * 512 + tk] = (acc[h] + sbias[h]) * 0.08838834764831845f;
  }
}

__global__ void k_smax(float* __restrict__ sc) {
  const int bh = blockIdx.x, tid = threadIdx.x;
  __shared__ float red[8];
  __shared__ float st0, st1;
  float v = sc[(size_t)bh * 512 + tid];
  float m = v;
  for (int k = 32; k > 0; k >>= 1) m = fmaxf(m, __shfl_xor(m, k));
  if ((tid & 63) == 0) red[tid >> 6] = m;
  __syncthreads();
  if (tid == 0) { float mm = red[0]; for (int i = 1; i < 8; ++i) mm = fmaxf(mm, red[i]); st0 = mm; }
  __syncthreads();
  float e = expf(v - st0);
  float s = e;
  for (int k = 32; k > 0; k >>= 1) s += __shfl_xor(s, k);
  if ((tid & 63) == 0) red[tid >> 6] = s;
  __syncthreads();
  if (tid == 0) { float ss = 0.f; for (int i = 0; i < 8; ++i) ss += red[i]; st1 = 1.f / ss; }
  __syncthreads();
  sc[(size_t)bh * 512 + tid] = e * st1;
}

__global__ void k_ebar(const float* __restrict__ sc, const float* __restrict__ enc,
                       float* __restrict__ ebar) {
  const int bh = blockIdx.x, tid = threadIdx.x;
  __shared__ float la[512];
  la[tid] = sc[(size_t)bh * 512 + tid];
  __syncthreads();
  const int b = bh >> 2;
  const float* eb = enc + (size_t)b * 512 * 512 + tid;
  float acc = 0.f;
  #pragma unroll 8
  for (int tk = 0; tk < 512; ++tk) acc = fmaf(la[tk], eb[(size_t)tk * 512], acc);
  ebar[(size_t)bh * 512 + tid] = acc;
}

// ---- fused vout+oproj+dgate: per-batch, LDS hand-off (3 GEMVs, 1 launch) ----
__global__ __launch_bounds__(1024) void k_avx(
    const float* __restrict__ aiw, const float* __restrict__ aib,
    const float* __restrict__ aow, const float* __restrict__ aob,
    const float* __restrict__ dwih, const float* __restrict__ db1,
    const float* __restrict__ db2, const float* __restrict__ ebar,
    float* __restrict__ xgd) {
  const int b = blockIdx.x, tid = threadIdx.x;
  __shared__ float leb[2048];
  __shared__ float lvo[512];
  __shared__ float lav[512];
  leb[tid] = ebar[(size_t)b * 2048 + tid];
  leb[1024 + tid] = ebar[(size_t)b * 2048 + 1024 + tid];
  __syncthreads();
  if (tid < 512) {                 // stage 1: vo[c] = wv[c]·ebar[b,c>>7] + bv[c]
    const int h = tid >> 7;
    const float4* w4 = (const float4*)(aiw + (size_t)(1024 + tid) * 512);
    const float4* e4 = (const float4*)(leb + h * 512);
    float acc = aib[1024 + tid];
    #pragma unroll 4
    for (int e = 0; e < 128; ++e) {
      float4 ww = w4[e], ee = e4[e];
      acc = fmaf(ww.x, ee.x, acc); acc = fmaf(ww.y, ee.y, acc);
      acc = fmaf(ww.z, ee.z, acc); acc = fmaf(ww.w, ee.w, acc);
    }
    lvo[tid] = acc;
  }
  __syncthreads();
  if (tid < 512) {                 // stage 2: av[e] = out_w[e]·vo + out_b[e]
    const float4* w4 = (const float4*)(aow + (size_t)tid * 512);
    const float4* v4 = (const float4*)lvo;
    float acc = aob[tid];
    #pragma unroll 4
    for (int e = 0; e < 128; ++e) {
      float4 ww = w4[e], ee = v4[e];
      acc = fmaf(ww.x, ee.x, acc); acc = fmaf(ww.y, ee.y, acc);
      acc = fmaf(ww.z, ee.z, acc); acc = fmaf(ww.w, ee.w, acc);
    }
    lav[tid] = acc;
  }
  __syncthreads();
  {                                 // stage 3: xgd[G] = dwih[G]·av + dbih[G]+dbhh[G]
    const int G = tid;
    const float4* w4 = (const float4*)(dwih + (size_t)G * 512);
    const float4* a4 = (const float4*)lav;
    float acc = db1[G] + db2[G];
    #pragma unroll 4
    for (int e = 0; e < 128; ++e) {
      float4 ww = w4[e], aa = a4[e];
      acc = fmaf(ww.x, aa.x, acc); acc = fmaf(ww.y, aa.y, acc);
      acc = fmaf(ww.z, aa.z, acc); acc = fmaf(ww.w, aa.w, acc);
    }
    xgd[(size_t)b * 1024 + G] = acc;
  }
}

// ---- decoder scan: 32 chains x 4 slices = 128 WGs; packed (tag|h) sync ----
__global__ __launch_bounds__(1024, 4) void k_dec(
    const float* __restrict__ dwpk, const float* __restrict__ xgd,
    float* __restrict__ dech, unsigned long long* __restrict__ hg) {
  const int wg = blockIdx.x;
  const int b = wg & 31, s = wg >> 5;          // slice-major: chain's WGs share wg%8 XCD
  const int tid = threadIdx.x;
  const int q = tid >> 8;
  __shared__ float sh_h[256];
  __shared__ float sh_p[1024];
  __shared__ float sh_a[256];
  float w[64];
  {
    const float* wp = dwpk + ((size_t)(s * 1024 + tid)) * 64;
    #pragma unroll
    for (int i = 0; i < 64; ++i) w[i] = wp[i];
  }
  float xg = 0.f;
  if (tid < 256)
    xg = xgd[(size_t)b * 1024 + ((tid >> 6) * 256 + s * 64 + (tid & 63))];
  if (tid < 256) sh_h[tid] = 0.f;
  float cst = 0.f;
  unsigned long long* hgc = hg + (size_t)b * 512;
  int budget = 20000000;
  __syncthreads();
  for (int t = 0; t < 1000; ++t) {
    float a0 = 0.f, a1 = 0.f, a2 = 0.f, a3 = 0.f;
    const float* hc = sh_h + q * 64;
    #pragma unroll
    for (int i0 = 0; i0 < 64; i0 += 16) {
      float4 h0 = *(const float4*)(hc + i0);
      float4 h1 = *(const float4*)(hc + i0 + 4);
      float4 h2 = *(const float4*)(hc + i0 + 8);
      float4 h3 = *(const float4*)(hc + i0 + 12);
      a0 = fmaf(w[i0+0], h0.x, a0); a0 = fmaf(w[i0+1], h0.y, a0); a0 = fmaf(w[i0+2], h0.z, a0); a0 = fmaf(w[i0+3], h0.w, a0);
      a1 = fmaf(w[i0+4], h1.x, a1); a1 = fmaf(w[i0+5], h1.y, a1); a1 = fmaf(w[i0+6], h1.z, a1); a1 = fmaf(w[i0+7], h1.w, a1);
      a2 = fmaf(w[i0+8], h2.x, a2); a2 = fmaf(w[i0+9], h2.y, a2); a2 = fmaf(w[i0+10], h2.z, a2); a2 = fmaf(w[i0+11], h2.w, a2);
      a3 = fmaf(w[i0+12], h3.x, a3); a3 = fmaf(w[i0+13], h3.y, a3); a3 = fmaf(w[i0+14], h3.z, a3); a3 = fmaf(w[i0+15], h3.w, a3);
    }
    sh_p[tid] = (a0 + a1) + (a2 + a3);
    __syncthreads();
    if (tid < 256) {
      float g = ((sh_p[tid] + sh_p[256 + tid]) + (sh_p[512 + tid] + sh_p[768 + tid])) + xg;
      sh_a[tid] = ((tid >> 6) == 2) ? tanhf(g) : sigm(g);
    }
    __syncthreads();
    if (tid < 64) {
      float ig = sh_a[tid], fg = sh_a[64 + tid], gg = sh_a[128 + tid], og = sh_a[192 + tid];
      cst = fg * cst + ig * gg;
      float hn = og * tanhf(cst);
      if (t < 999)
        __hip_atomic_store(&hgc[(t & 1) * 256 + s * 64 + tid], packh(hn, (unsigned)(t + 1)),
                           __ATOMIC_RELAXED, __HIP_MEMORY_SCOPE_AGENT);
      dech[((size_t)b * 1000 + t) * 256 + s * 64 + tid] = hn;   // off crit. path
    }
    if (t < 999) {
      if (tid < 256) {
        const unsigned tgt = (unsigned)(t + 1);
        unsigned long long v;
        for (;;) {
          v = __hip_atomic_load(&hgc[(t & 1) * 256 + tid],
                                __ATOMIC_RELAXED, __HIP_MEMORY_SCOPE_AGENT);
          if ((unsigned)(v >> 32) == tgt || --budget <= 0) break;
          __builtin_amdgcn_s_sleep(1);
        }
        fu32 c; c.u = (unsigned)v;
        sh_h[tid] = c.f;
      }
      __syncthreads();
    }
  }
}

// ---- projection: out = dech @ proj_w^T + proj_b, FLOAT32 out ----
__global__ __launch_bounds__(256) void k_proj(const float* __restrict__ dech,
                                              const float* __restrict__ pw,
                                              const float* __restrict__ pb,
                                              float* __restrict__ out) {
  __shared__ float lpw[80 * 260];
  __shared__ float lpb[80];
  const int tid = threadIdx.x;
  for (int i = tid; i < 20480; i += 256) lpw[(i >> 8) * 260 + (i & 255)] = pw[i];
  if (tid < 80) lpb[tid] = pb[tid];
  __syncthreads();
  const int row0 = blockIdx.x * 16;
  const int ri = tid >> 4, mi = tid & 15;
  const float4* dr = (const float4*)(dech + (size_t)(row0 + ri) * 256);
  #pragma unroll
  for (int mt = 0; mt < 5; ++mt) {
    const int m = mt * 16 + mi;
    float acc = lpb[m];
    const float4* pw4 = (const float4*)&lpw[m * 260];
    #pragma unroll 8
    for (int d4 = 0; d4 < 64; ++d4) {
      float4 w4 = pw4[d4]; float4 x4 = dr[d4];
      acc = fmaf(w4.x, x4.x, acc); acc = fmaf(w4.y, x4.y, acc);
      acc = fmaf(w4.z, x4.z, acc); acc = fmaf(w4.w, x4.w, acc);
    }
    out[(size_t)(row0 + ri) * 80 + m] = acc;
  }
}

extern "C" void kernel_launch(void* const* d_in, const int* in_sizes, int n_in,
                              void* d_out, int out_size, void* d_ws, size_t ws_size,
                              hipStream_t stream) {
  static const int SIG[21] = {16384, 2560000, 65536,
                              262144, 262144, 1024, 1024,      // enc_f
                              262144, 262144, 1024, 1024,      // enc_b
                              786432, 1536, 262144, 512,       // attn
                              524288, 262144, 1024, 1024,      // dec
                              20480, 80};                      // proj
  if (n_in != 21) return;
  for (int i = 0; i < 21; ++i) if (in_sizes[i] != SIG[i]) return;
  if (ws_size < O_END * sizeof(float)) return;
  if (out_size != 32 * 1000 * 80) return;

  const int* text = (const int*)d_in[0];
  const float* emb    = (const float*)d_in[2];
  const float* ef_wih = (const float*)d_in[3];
  const float* ef_whh = (const float*)d_in[4];
  const float* ef_bih = (const float*)d_in[5];
  const float* ef_bhh = (const float*)d_in[6];
  const float* eb_wih = (const float*)d_in[7];
  const float* eb_whh = (const float*)d_in[8];
  const float* eb_bih = (const float*)d_in[9];
  const float* eb_bhh = (const float*)d_in[10];
  const float* aiw    = (const float*)d_in[11];
  const float* aib    = (const float*)d_in[12];
  const float* aow    = (const float*)d_in[13];
  const float* aob    = (const float*)d_in[14];
  const float* dwih   = (const float*)d_in[15];
  const float* dwhh   = (const float*)d_in[16];
  const float* dbih   = (const float*)d_in[17];
  const float* dbhh   = (const float*)d_in[18];
  const float* pw     = (const float*)d_in[19];
  const float* pb     = (const float*)d_in[20];
  float* W = (float*)d_ws;
  unsigned long long* hge = (unsigned long long*)(W + O_HGE);
  unsigned long long* hgd = (unsigned long long*)(W + O_HGD);
  float* out = (float*)d_out;

  k_prepA<<<3072, 256, 0, stream>>>(ef_whh, eb_whh, dwhh, W + O_EWPK, W + O_DWPK);
  k_prepB<<<2048, 256, 0, stream>>>(emb, ef_wih, ef_bih, ef_bhh,
                                    eb_wih, eb_bih, eb_bhh, W + O_EGT);
  k_enc<<<256, 1024, 0, stream>>>(W + O_EWPK, W + O_EGT, text, W + O_ENC, hge);
  k_att1<<<4, 512, 0, stream>>>(aiw, aib, W + O_U, W + O_SB);
  k_att2<<<4096, 256, 0, stream>>>(W + O_ENC, W + O_U, W + O_SB, W + O_SC);
  k_smax<<<128, 512, 0, stream>>>(W + O_SC);
  k_ebar<<<128, 512, 0, stream>>>(W + O_SC, W + O_ENC, W + O_EBAR);
  k_avx<<<32, 1024, 0, stream>>>(aiw, aib, aow, aob, dwih, dbih, dbhh,
                                 W + O_EBAR, W + O_XGD);
  k_dec<<<128, 1024, 0, stream>>>(W + O_DWPK, W + O_XGD, W + O_DECH, hgd);
  k_proj<<<2000, 256, 0, stream>>>(W + O_DECH, pw, pb, out);
}